// Round 6
// baseline (148.358 us; speedup 1.0000x reference)
//
#include <hip/hip_runtime.h>
#include <hip/hip_bf16.h>
#include <stdint.h>
#include <math.h>

#define NHEAD 16
#define DK 64
#define SEQ 2048
#define BATCH 2
#define DMODEL 1024

typedef __attribute__((ext_vector_type(8))) short short8_t;
typedef __attribute__((ext_vector_type(4))) float f32x4;

#define MFMA(a, b, c) __builtin_amdgcn_mfma_f32_16x16x32_bf16(a, b, c, 0, 0, 0)

__device__ __forceinline__ unsigned short f2bf(float f) {
    union { __hip_bfloat16 b; unsigned short u; } c;
    c.b = __float2bfloat16(f);
    return c.u;
}

// ---------------------------------------------------------------------------
// bucket_kernel: per (bh, which) stable-partition indices by hash value.
// order[pos] = original index. cnts[which*32+bh] = #zeros.
// ---------------------------------------------------------------------------
__global__ __launch_bounds__(256) void bucket_kernel(
    const int* __restrict__ hq, const int* __restrict__ hk,
    int* __restrict__ qorder, int* __restrict__ korder, int* __restrict__ cnts)
{
    const int blk = blockIdx.x;          // 0..63
    const int bh = blk >> 1;
    const int which = blk & 1;
    const int* src = (which ? hk : hq) + (size_t)bh * SEQ;
    int* dst = (which ? korder : qorder) + (size_t)bh * SEQ;

    __shared__ int cnt[257];
    const int t = threadIdx.x;           // 0..255
    int h[8]; int c = 0;
#pragma unroll
    for (int j = 0; j < 8; j++) { h[j] = src[t * 8 + j]; c += (h[j] == 0); }
    cnt[t] = c;
    __syncthreads();
    if (t == 0) {
        int run = 0;
        for (int i = 0; i < 256; i++) { int v = cnt[i]; cnt[i] = run; run += v; }
        cnt[256] = run;
    }
    __syncthreads();
    const int nz = cnt[256];
    int zpos = cnt[t];
    int opos = nz + t * 8 - cnt[t];
#pragma unroll
    for (int j = 0; j < 8; j++) {
        int idx = t * 8 + j;
        if (h[j] == 0) dst[zpos++] = idx; else dst[opos++] = idx;
    }
    if (t == 0) cnts[which * 32 + bh] = nz;
}

// ---------------------------------------------------------------------------
// cvt_xw: X (4M f32) -> bf16, W (1M f32) -> bf16.
// ---------------------------------------------------------------------------
__global__ __launch_bounds__(256) void cvt_xw_kernel(
    const float* __restrict__ X, const float* __restrict__ W,
    unsigned short* __restrict__ Xb, unsigned short* __restrict__ Wb)
{
    const size_t t = (size_t)blockIdx.x * 256 + threadIdx.x;
    const float* src;
    unsigned short* dst;
    size_t i8;
    if (t < 524288) { src = X; dst = Xb; i8 = t * 8; }
    else            { src = W; dst = Wb; i8 = (t - 524288) * 8; }
    f32x4 v0 = *(const f32x4*)(src + i8);
    f32x4 v1 = *(const f32x4*)(src + i8 + 4);
    union { short8_t v; unsigned short u[8]; } o;
#pragma unroll
    for (int j = 0; j < 4; j++) {
        o.u[j]     = f2bf(v0[j]);
        o.u[4 + j] = f2bf(v1[j]);
    }
    *(short8_t*)(dst + i8) = o.v;
}

// ---------------------------------------------------------------------------
// proj_perm_nt: dst[b,h,pos,d] = (Xb[order] @ Wb^T + bias) in SORTED row order.
// Tile 128(M sorted rows, one b) x 64(N = one head), BK=64, 4 waves.
// A rows loaded through per-head permutation (per-lane gld_lds source).
// ---------------------------------------------------------------------------
__global__ __launch_bounds__(256) void proj_perm_nt(
    const unsigned short* __restrict__ Xb,   // [4096][1024]
    const unsigned short* __restrict__ Wb,   // [1024][1024]
    const float* __restrict__ bias,
    const int* __restrict__ order,           // [32][2048]
    unsigned short* __restrict__ dst)        // [b,h,pos,d] bf16
{
    __shared__ unsigned short At[128 * 64];
    __shared__ unsigned short Bt[64 * 64];

    const int tid = threadIdx.x;
    const int lane = tid & 63;
    const int wv = tid >> 6;
    const int fr = lane & 15;
    const int fg = lane >> 4;
    const int m0 = blockIdx.y * 128;        // sorted-row tile (within one b)
    const int head = blockIdx.x;            // 0..15
    const int bb = m0 >> 11;
    const int bh = bb * NHEAD + head;
    const int n0 = head * 64;
    const int srw = lane >> 3;
    const int su = lane & 7;
    const int mloc = m0 & (SEQ - 1);
    const int* ordp = order + (size_t)bh * SEQ + mloc;

    f32x4 acc[2][4];
    const f32x4 fzero = {0.f, 0.f, 0.f, 0.f};
#pragma unroll
    for (int mf = 0; mf < 2; mf++)
#pragma unroll
        for (int nf = 0; nf < 4; nf++) acc[mf][nf] = fzero;

    for (int k0 = 0; k0 < DMODEL; k0 += 64) {
#pragma unroll
        for (int i = 0; i < 4; i++) {
            int r = wv * 32 + i * 8 + srw;
            int src_l = ordp[r];                          // permuted source row
            const unsigned short* g =
                Xb + (size_t)(bb * SEQ + src_l) * DMODEL + k0 + ((su ^ (r & 7)) << 3);
            __builtin_amdgcn_global_load_lds(
                (const void*)g, (void*)&At[(wv * 32 + i * 8) * 64], 16, 0, 0);
        }
#pragma unroll
        for (int i = 0; i < 2; i++) {
            int r = wv * 16 + i * 8 + srw;
            const unsigned short* g =
                Wb + (size_t)(n0 + r) * DMODEL + k0 + ((su ^ (r & 7)) << 3);
            __builtin_amdgcn_global_load_lds(
                (const void*)g, (void*)&Bt[(wv * 16 + i * 8) * 64], 16, 0, 0);
        }
        __syncthreads();

        short8_t a[2][2], b[4][2];
#pragma unroll
        for (int mf = 0; mf < 2; mf++)
#pragma unroll
            for (int ks = 0; ks < 2; ks++) {
                int r = wv * 32 + mf * 16 + fr;
                int u = (ks * 4 + fg) ^ (fr & 7);
                a[mf][ks] = *(const short8_t*)&At[r * 64 + u * 8];
            }
#pragma unroll
        for (int nf = 0; nf < 4; nf++)
#pragma unroll
            for (int ks = 0; ks < 2; ks++) {
                int r = nf * 16 + fr;
                int u = (ks * 4 + fg) ^ (fr & 7);
                b[nf][ks] = *(const short8_t*)&Bt[r * 64 + u * 8];
            }
#pragma unroll
        for (int ks = 0; ks < 2; ks++)
#pragma unroll
            for (int mf = 0; mf < 2; mf++)
#pragma unroll
                for (int nf = 0; nf < 4; nf++)
                    acc[mf][nf] = MFMA(a[mf][ks], b[nf][ks], acc[mf][nf]);
        __syncthreads();
    }

    // epilogue: sorted row pos = mloc + wv*32 + mf*16 + fg*4 + r ; col d = nf*16+fr
#pragma unroll
    for (int mf = 0; mf < 2; mf++)
#pragma unroll
        for (int nf = 0; nf < 4; nf++)
#pragma unroll
            for (int r = 0; r < 4; r++) {
                int pos = mloc + wv * 32 + mf * 16 + fg * 4 + r;
                int dd = nf * 16 + fr;
                float v = acc[mf][nf][r] + bias[n0 + dd];
                dst[((size_t)bh * SEQ + pos) * DK + dd] = f2bf(v);
            }
}

// ---------------------------------------------------------------------------
// proj_perm_tn: dstT[b,h,d,pos] = (Xb[korder] @ Wb^T + bias)^T, sorted cols.
// A = W tile 64 (one head), B = X tile 128 sorted rows, BK=64, 4 waves.
// Wave owns 16 o-rows x 128 cols (acc[8]).
// ---------------------------------------------------------------------------
__global__ __launch_bounds__(256) void proj_perm_tn(
    const unsigned short* __restrict__ Xb,   // [4096][1024]
    const unsigned short* __restrict__ Wb,   // [1024][1024]
    const float* __restrict__ bias,
    const int* __restrict__ order,           // [32][2048]
    unsigned short* __restrict__ dstT)       // [b,h,d,pos] bf16
{
    __shared__ unsigned short At[64 * 64];
    __shared__ unsigned short Bt[128 * 64];

    const int tid = threadIdx.x;
    const int lane = tid & 63;
    const int wv = tid >> 6;
    const int fr = lane & 15;
    const int fg = lane >> 4;
    const int m0 = blockIdx.x * 128;        // sorted key tile (within one b)
    const int head = blockIdx.y;
    const int bb = m0 >> 11;
    const int bh = bb * NHEAD + head;
    const int o0 = head * 64;
    const int srw = lane >> 3;
    const int su = lane & 7;
    const int mloc = m0 & (SEQ - 1);
    const int* ordp = order + (size_t)bh * SEQ + mloc;

    f32x4 acc[8];
    const f32x4 fzero = {0.f, 0.f, 0.f, 0.f};
#pragma unroll
    for (int nf = 0; nf < 8; nf++) acc[nf] = fzero;

    for (int k0 = 0; k0 < DMODEL; k0 += 64) {
#pragma unroll
        for (int i = 0; i < 2; i++) {
            int r = wv * 16 + i * 8 + srw;
            const unsigned short* g =
                Wb + (size_t)(o0 + r) * DMODEL + k0 + ((su ^ (r & 7)) << 3);
            __builtin_amdgcn_global_load_lds(
                (const void*)g, (void*)&At[(wv * 16 + i * 8) * 64], 16, 0, 0);
        }
#pragma unroll
        for (int i = 0; i < 4; i++) {
            int r = wv * 32 + i * 8 + srw;
            int src_l = ordp[r];
            const unsigned short* g =
                Xb + (size_t)(bb * SEQ + src_l) * DMODEL + k0 + ((su ^ (r & 7)) << 3);
            __builtin_amdgcn_global_load_lds(
                (const void*)g, (void*)&Bt[(wv * 32 + i * 8) * 64], 16, 0, 0);
        }
        __syncthreads();

        short8_t a[2];
#pragma unroll
        for (int ks = 0; ks < 2; ks++) {
            int r = wv * 16 + fr;
            int u = (ks * 4 + fg) ^ (fr & 7);
            a[ks] = *(const short8_t*)&At[r * 64 + u * 8];
        }
#pragma unroll
        for (int nf = 0; nf < 8; nf++) {
#pragma unroll
            for (int ks = 0; ks < 2; ks++) {
                int r = nf * 16 + fr;
                int u = (ks * 4 + fg) ^ (fr & 7);
                short8_t b = *(const short8_t*)&Bt[r * 64 + u * 8];
                acc[nf] = MFMA(a[ks], b, acc[nf]);
            }
        }
        __syncthreads();
    }

    // epilogue: od = o0 + wv*16 + fg*4 + r ; col pos = mloc + nf*16 + fr
#pragma unroll
    for (int nf = 0; nf < 8; nf++)
#pragma unroll
        for (int r = 0; r < 4; r++) {
            int dd = wv * 16 + fg * 4 + r;
            int pos = mloc + nf * 16 + fr;
            float v = acc[nf][r] + bias[o0 + dd];
            dstT[((size_t)bh * DK + dd) * SEQ + pos] = f2bf(v);
        }
}

// ---------------------------------------------------------------------------
// LSH flash attention over bucket-sorted Q/K/V: two dense rectangles.
// Grid 1024 flat XCD-swizzled; 4 waves; wave w = sorted q-rows [q0+w*16,+16).
// Per-wave key-tile range from bucket boundary; position-compare masking
// only matters in boundary tiles / the (<=1 per head) mixed wave.
// ---------------------------------------------------------------------------
__global__ __launch_bounds__(256) void lsh_attn_kernel(
    const unsigned short* __restrict__ Qs,
    const unsigned short* __restrict__ Ks, const unsigned short* __restrict__ Vst,
    const int* __restrict__ qorder, const int* __restrict__ cnts,
    float* __restrict__ out)
{
    __shared__ unsigned short KtL[64 * 64];
    __shared__ unsigned short VtL[64 * 64];
    __shared__ unsigned short Pl[4][16][72];

    const int tid = threadIdx.x;
    const int lane = tid & 63;
    const int wv = tid >> 6;
    const int fr = lane & 15;
    const int fg = lane >> 4;

    const int flat = blockIdx.x;                 // 0..1023
    const int xcd = flat & 7;
    const int slot = flat >> 3;                  // 0..127
    const int bh = (xcd << 2) + (slot >> 5);     // b*16 + h
    const int q0 = (slot & 31) << 6;             // sorted q-row base

    const int nq0 = cnts[bh];
    const int nk0 = cnts[32 + bh];

    const size_t base = (size_t)bh * SEQ * DK;
    const unsigned short* Kb = Ks + base;                    // [pos][d]
    const unsigned short* Vb = Vst + (size_t)bh * DK * SEQ;  // [d][pos]

    const int srw = lane >> 3;
    const int su = lane & 7;

    // Q fragments (sorted rows q0 + wv*16 + fr)
    short8_t q_hi[2];
    {
        const size_t ro = base + (size_t)(q0 + wv * 16 + fr) * DK;
        q_hi[0] = *(const short8_t*)(Qs + ro + fg * 8);
        q_hi[1] = *(const short8_t*)(Qs + ro + 32 + fg * 8);
    }
    // row buckets (0/1) for this thread's 4 C-rows
    int rb[4];
#pragma unroll
    for (int r = 0; r < 4; r++)
        rb[r] = (q0 + wv * 16 + fg * 4 + r) >= nq0;

    // tile ranges
    const int ceil0 = (nk0 + 63) >> 6;            // tiles covering bucket 0
    const int floor1 = nk0 >> 6;                  // first tile touching bucket 1
    const int bfirst = (q0 >= nq0), blast = (q0 + 63 >= nq0);
    const int bklo = bfirst ? floor1 : 0;
    const int bkhi = blast ? 32 : ceil0;
    const int wfirst = (q0 + wv * 16 >= nq0), wlast = (q0 + wv * 16 + 15 >= nq0);
    const int wklo = wfirst ? floor1 : 0;
    const int wkhi = wlast ? 32 : ceil0;

    const int swz = fr & 7;
    const int u0 = ((fg ^ swz) << 3);
    const int u1 = (((4 + fg) ^ swz) << 3);

    const float C2 = 0.18033688011112042f;    // 0.125 * log2(e)
    const float B2 = -14.426950408889634f;    // -10 * log2(e)

    float psum[4] = {0.f, 0.f, 0.f, 0.f};
    f32x4 o_acc[4];
    const f32x4 fzero = {0.f, 0.f, 0.f, 0.f};
#pragma unroll
    for (int t = 0; t < 4; t++) o_acc[t] = fzero;

    for (int t = bklo; t < bkhi; t++) {
        const int k0 = t << 6;
        // ---- cooperative stage: wave wv stages rows [wv*16, +16) ----
#pragma unroll
        for (int i = 0; i < 2; i++) {
            const int r = wv * 16 + i * 8 + srw;
            const int uo = ((su ^ (r & 7)) << 3);
            const unsigned short* gk = Kb + (size_t)(k0 + r) * DK + uo;
            const unsigned short* gv = Vb + (size_t)r * SEQ + k0 + uo;
            __builtin_amdgcn_global_load_lds(
                (const void*)gk, (void*)&KtL[(wv * 16 + i * 8) * 64], 16, 0, 0);
            __builtin_amdgcn_global_load_lds(
                (const void*)gv, (void*)&VtL[(wv * 16 + i * 8) * 64], 16, 0, 0);
        }
        __syncthreads();

        if (t >= wklo && t < wkhi) {
            // ---- S = Q K^T (8 MFMA) ----
            f32x4 s[4];
#pragma unroll
            for (int kg = 0; kg < 4; kg++) {
                const int rr = (kg * 16 + fr) * 64;
                short8_t kc0 = *(const short8_t*)&KtL[rr + u0];
                short8_t kc1 = *(const short8_t*)&KtL[rr + u1];
                f32x4 a = fzero;
                a = MFMA(q_hi[0], kc0, a);
                a = MFMA(q_hi[1], kc1, a);
                s[kg] = a;
            }

            // ---- softmax: p = exp2(s*C2 + B2), bucket-match masked ----
            int cb[4];
#pragma unroll
            for (int kg = 0; kg < 4; kg++) cb[kg] = (k0 + kg * 16 + fr) >= nk0;
#pragma unroll
            for (int r = 0; r < 4; r++) {
#pragma unroll
                for (int kg = 0; kg < 4; kg++) {
                    float basev = (rb[r] == cb[kg]) ? B2 : -1e9f;
                    float p = exp2f(fmaf(s[kg][r], C2, basev));
                    psum[r] += p;
                    Pl[wv][fg * 4 + r][kg * 16 + fr] = f2bf(p);
                }
            }

            // ---- O += P V ----
            short8_t pa0 = *(const short8_t*)&Pl[wv][fr][fg * 8];
            short8_t pa1 = *(const short8_t*)&Pl[wv][fr][32 + fg * 8];
#pragma unroll
            for (int dt = 0; dt < 4; dt++) {
                const int rr = (dt * 16 + fr) * 64;
                short8_t v0 = *(const short8_t*)&VtL[rr + u0];
                short8_t v1 = *(const short8_t*)&VtL[rr + u1];
                o_acc[dt] = MFMA(pa0, v0, o_acc[dt]);
                o_acc[dt] = MFMA(pa1, v1, o_acc[dt]);
            }
        }
        __syncthreads();
    }

    // ---- final l-reduction over the 16 fr lanes ----
#pragma unroll
    for (int d = 1; d < 16; d <<= 1) {
#pragma unroll
        for (int r = 0; r < 4; r++) psum[r] += __shfl_xor(psum[r], d, 64);
    }

    // ---- epilogue: scatter rows back via qorder ----
    const int b = bh >> 4, h = bh & 15;
#pragma unroll
    for (int r = 0; r < 4; r++) {
        const int qpos = q0 + wv * 16 + fg * 4 + r;
        const int origq = qorder[(size_t)bh * SEQ + qpos];
        const float inv = 1.0f / psum[r];
#pragma unroll
        for (int dt = 0; dt < 4; dt++) {
            int dcol = dt * 16 + fr;
            out[((size_t)(b * SEQ + origq)) * DMODEL + h * DK + dcol] =
                o_acc[dt][r] * inv;
        }
    }
}

// ---------------------------------------------------------------------------

extern "C" void kernel_launch(void* const* d_in, const int* in_sizes, int n_in,
                              void* d_out, int out_size, void* d_ws, size_t ws_size,
                              hipStream_t stream)
{
    const float* query = (const float*)d_in[0];
    const float* key   = (const float*)d_in[1];
    const float* value = (const float*)d_in[2];
    const int* hash_q  = (const int*)d_in[3];
    const int* hash_k  = (const int*)d_in[4];
    const float* Wq    = (const float*)d_in[5];
    const float* bq    = (const float*)d_in[6];
    const float* Wk    = (const float*)d_in[7];
    const float* bk    = (const float*)d_in[8];
    const float* Wv    = (const float*)d_in[9];
    const float* bv    = (const float*)d_in[10];
    float* out = (float*)d_out;

    const size_t plane = (size_t)BATCH * NHEAD * SEQ * DK;   // 4,194,304 elems
    unsigned short* ws = (unsigned short*)d_ws;
    unsigned short* pQ    = ws;
    unsigned short* pK    = ws + plane;
    unsigned short* pVt   = ws + 2 * plane;
    unsigned short* Xslot = ws + 3 * plane;                   // 4M els
    unsigned short* Wslot = ws + 4 * plane;                   // 1M els
    int* ip = (int*)(ws + 4 * plane + (size_t)DMODEL * DMODEL);
    int* qorder = ip;                 // 32*2048
    int* korder = ip + 65536;         // 32*2048
    int* cnts   = ip + 131072;        // 64

    bucket_kernel<<<64, 256, 0, stream>>>(hash_q, hash_k, qorder, korder, cnts);

    dim3 gridN(NHEAD, (BATCH * SEQ) / 128);        // (16, 32)
    dim3 gridT((BATCH * SEQ) / 128, NHEAD);        // (32, 16)
    const int cvtBlocks = (int)((plane + (size_t)DMODEL * DMODEL) / 8 / 256);

    cvt_xw_kernel<<<cvtBlocks, 256, 0, stream>>>(query, Wq, Xslot, Wslot);
    proj_perm_nt<<<gridN, 256, 0, stream>>>(Xslot, Wslot, bq, qorder, pQ);

    cvt_xw_kernel<<<cvtBlocks, 256, 0, stream>>>(key, Wk, Xslot, Wslot);
    proj_perm_nt<<<gridN, 256, 0, stream>>>(Xslot, Wslot, bk, korder, pK);

    cvt_xw_kernel<<<cvtBlocks, 256, 0, stream>>>(value, Wv, Xslot, Wslot);
    proj_perm_tn<<<gridT, 256, 0, stream>>>(Xslot, Wslot, bv, korder, pVt);

    lsh_attn_kernel<<<dim3(1024), 256, 0, stream>>>(pQ, pK, pVt,
                                                    qorder, cnts, out);
}

// Round 7
// 134.166 us; speedup vs baseline: 1.1058x; 1.1058x over previous
//
#include <hip/hip_runtime.h>
#include <hip/hip_bf16.h>
#include <stdint.h>
#include <math.h>

#define NHEAD 16
#define DK 64
#define SEQ 2048
#define BATCH 2
#define DMODEL 1024

typedef __attribute__((ext_vector_type(8))) short short8_t;
typedef __attribute__((ext_vector_type(4))) float f32x4;

#define MFMA(a, b, c) __builtin_amdgcn_mfma_f32_16x16x32_bf16(a, b, c, 0, 0, 0)

__device__ __forceinline__ unsigned short f2bf(float f) {
    union { __hip_bfloat16 b; unsigned short u; } c;
    c.b = __float2bfloat16(f);
    return c.u;
}

// ---------------------------------------------------------------------------
// bucket_kernel: per (bh, which) stable-partition indices by hash value.
// order[pos] = original index. cnts[which*32+bh] = #zeros.
// ---------------------------------------------------------------------------
__global__ __launch_bounds__(256) void bucket_kernel(
    const int* __restrict__ hq, const int* __restrict__ hk,
    int* __restrict__ qorder, int* __restrict__ korder, int* __restrict__ cnts)
{
    const int blk = blockIdx.x;          // 0..63
    const int bh = blk >> 1;
    const int which = blk & 1;
    const int* src = (which ? hk : hq) + (size_t)bh * SEQ;
    int* dst = (which ? korder : qorder) + (size_t)bh * SEQ;

    __shared__ int cnt[257];
    const int t = threadIdx.x;           // 0..255
    int h[8]; int c = 0;
#pragma unroll
    for (int j = 0; j < 8; j++) { h[j] = src[t * 8 + j]; c += (h[j] == 0); }
    cnt[t] = c;
    __syncthreads();
    if (t == 0) {
        int run = 0;
        for (int i = 0; i < 256; i++) { int v = cnt[i]; cnt[i] = run; run += v; }
        cnt[256] = run;
    }
    __syncthreads();
    const int nz = cnt[256];
    int zpos = cnt[t];
    int opos = nz + t * 8 - cnt[t];
#pragma unroll
    for (int j = 0; j < 8; j++) {
        int idx = t * 8 + j;
        if (h[j] == 0) dst[zpos++] = idx; else dst[opos++] = idx;
    }
    if (t == 0) cnts[which * 32 + bh] = nz;
}

// ---------------------------------------------------------------------------
// cvt_xw: X (4M f32) -> bf16, W (1M f32) -> bf16.
// ---------------------------------------------------------------------------
__global__ __launch_bounds__(256) void cvt_xw_kernel(
    const float* __restrict__ X, const float* __restrict__ W,
    unsigned short* __restrict__ Xb, unsigned short* __restrict__ Wb)
{
    const size_t t = (size_t)blockIdx.x * 256 + threadIdx.x;
    const float* src;
    unsigned short* dst;
    size_t i8;
    if (t < 524288) { src = X; dst = Xb; i8 = t * 8; }
    else            { src = W; dst = Wb; i8 = (t - 524288) * 8; }
    f32x4 v0 = *(const f32x4*)(src + i8);
    f32x4 v1 = *(const f32x4*)(src + i8 + 4);
    union { short8_t v; unsigned short u[8]; } o;
#pragma unroll
    for (int j = 0; j < 4; j++) {
        o.u[j]     = f2bf(v0[j]);
        o.u[4 + j] = f2bf(v1[j]);
    }
    *(short8_t*)(dst + i8) = o.v;
}

// ---------------------------------------------------------------------------
// proj_perm_nt: dst[b,h,pos,d] = (Xb[order] @ Wb^T + bias) in SORTED row order.
// Tile 128 x 64 (one head), BK=64, 4 waves. Permuted source addresses HOISTED.
// ---------------------------------------------------------------------------
__global__ __launch_bounds__(256) void proj_perm_nt(
    const unsigned short* __restrict__ Xb,   // [4096][1024]
    const unsigned short* __restrict__ Wb,   // [1024][1024]
    const float* __restrict__ bias,
    const int* __restrict__ order,           // [32][2048]
    unsigned short* __restrict__ dst)        // [b,h,pos,d] bf16
{
    __shared__ unsigned short At[128 * 64];
    __shared__ unsigned short Bt[64 * 64];

    const int tid = threadIdx.x;
    const int lane = tid & 63;
    const int wv = tid >> 6;
    const int fr = lane & 15;
    const int fg = lane >> 4;
    const int m0 = blockIdx.y * 128;        // sorted-row tile (within one b)
    const int head = blockIdx.x;            // 0..15
    const int bb = m0 >> 11;
    const int bh = bb * NHEAD + head;
    const int n0 = head * 64;
    const int srw = lane >> 3;
    const int su = lane & 7;
    const int mloc = m0 & (SEQ - 1);
    const int* ordp = order + (size_t)bh * SEQ + mloc;

    // hoisted per-lane source bases (K-invariant)
    const unsigned short* aSrc[4];
#pragma unroll
    for (int i = 0; i < 4; i++) {
        int r = wv * 32 + i * 8 + srw;
        int src_l = ordp[r];
        aSrc[i] = Xb + (size_t)(bb * SEQ + src_l) * DMODEL + ((su ^ (r & 7)) << 3);
    }
    const unsigned short* bSrc[2];
#pragma unroll
    for (int i = 0; i < 2; i++) {
        int r = wv * 16 + i * 8 + srw;
        bSrc[i] = Wb + (size_t)(n0 + r) * DMODEL + ((su ^ (r & 7)) << 3);
    }

    f32x4 acc[2][4];
    const f32x4 fzero = {0.f, 0.f, 0.f, 0.f};
#pragma unroll
    for (int mf = 0; mf < 2; mf++)
#pragma unroll
        for (int nf = 0; nf < 4; nf++) acc[mf][nf] = fzero;

    for (int k0 = 0; k0 < DMODEL; k0 += 64) {
#pragma unroll
        for (int i = 0; i < 4; i++)
            __builtin_amdgcn_global_load_lds(
                (const void*)(aSrc[i] + k0), (void*)&At[(wv * 32 + i * 8) * 64], 16, 0, 0);
#pragma unroll
        for (int i = 0; i < 2; i++)
            __builtin_amdgcn_global_load_lds(
                (const void*)(bSrc[i] + k0), (void*)&Bt[(wv * 16 + i * 8) * 64], 16, 0, 0);
        __syncthreads();

        short8_t a[2][2], b[4][2];
#pragma unroll
        for (int mf = 0; mf < 2; mf++)
#pragma unroll
            for (int ks = 0; ks < 2; ks++) {
                int r = wv * 32 + mf * 16 + fr;
                int u = (ks * 4 + fg) ^ (fr & 7);
                a[mf][ks] = *(const short8_t*)&At[r * 64 + u * 8];
            }
#pragma unroll
        for (int nf = 0; nf < 4; nf++)
#pragma unroll
            for (int ks = 0; ks < 2; ks++) {
                int r = nf * 16 + fr;
                int u = (ks * 4 + fg) ^ (fr & 7);
                b[nf][ks] = *(const short8_t*)&Bt[r * 64 + u * 8];
            }
#pragma unroll
        for (int ks = 0; ks < 2; ks++)
#pragma unroll
            for (int mf = 0; mf < 2; mf++)
#pragma unroll
                for (int nf = 0; nf < 4; nf++)
                    acc[mf][nf] = MFMA(a[mf][ks], b[nf][ks], acc[mf][nf]);
        __syncthreads();
    }

#pragma unroll
    for (int mf = 0; mf < 2; mf++)
#pragma unroll
        for (int nf = 0; nf < 4; nf++)
#pragma unroll
            for (int r = 0; r < 4; r++) {
                int pos = mloc + wv * 32 + mf * 16 + fg * 4 + r;
                int dd = nf * 16 + fr;
                float v = acc[mf][nf][r] + bias[n0 + dd];
                dst[((size_t)bh * SEQ + pos) * DK + dd] = f2bf(v);
            }
}

// ---------------------------------------------------------------------------
// proj_perm_tn: dstT[b,h,d,pos] = (Xb[korder] @ Wb^T + bias)^T, sorted cols.
// Hoisted permuted sources.
// ---------------------------------------------------------------------------
__global__ __launch_bounds__(256) void proj_perm_tn(
    const unsigned short* __restrict__ Xb,   // [4096][1024]
    const unsigned short* __restrict__ Wb,   // [1024][1024]
    const float* __restrict__ bias,
    const int* __restrict__ order,           // [32][2048]
    unsigned short* __restrict__ dstT)       // [b,h,d,pos] bf16
{
    __shared__ unsigned short At[64 * 64];
    __shared__ unsigned short Bt[128 * 64];

    const int tid = threadIdx.x;
    const int lane = tid & 63;
    const int wv = tid >> 6;
    const int fr = lane & 15;
    const int fg = lane >> 4;
    const int m0 = blockIdx.x * 128;        // sorted key tile (within one b)
    const int head = blockIdx.y;
    const int bb = m0 >> 11;
    const int bh = bb * NHEAD + head;
    const int o0 = head * 64;
    const int srw = lane >> 3;
    const int su = lane & 7;
    const int mloc = m0 & (SEQ - 1);
    const int* ordp = order + (size_t)bh * SEQ + mloc;

    const unsigned short* aSrc[2];
#pragma unroll
    for (int i = 0; i < 2; i++) {
        int r = wv * 16 + i * 8 + srw;
        aSrc[i] = Wb + (size_t)(o0 + r) * DMODEL + ((su ^ (r & 7)) << 3);
    }
    const unsigned short* bSrc[4];
#pragma unroll
    for (int i = 0; i < 4; i++) {
        int r = wv * 32 + i * 8 + srw;
        int src_l = ordp[r];
        bSrc[i] = Xb + (size_t)(bb * SEQ + src_l) * DMODEL + ((su ^ (r & 7)) << 3);
    }

    f32x4 acc[8];
    const f32x4 fzero = {0.f, 0.f, 0.f, 0.f};
#pragma unroll
    for (int nf = 0; nf < 8; nf++) acc[nf] = fzero;

    for (int k0 = 0; k0 < DMODEL; k0 += 64) {
#pragma unroll
        for (int i = 0; i < 2; i++)
            __builtin_amdgcn_global_load_lds(
                (const void*)(aSrc[i] + k0), (void*)&At[(wv * 16 + i * 8) * 64], 16, 0, 0);
#pragma unroll
        for (int i = 0; i < 4; i++)
            __builtin_amdgcn_global_load_lds(
                (const void*)(bSrc[i] + k0), (void*)&Bt[(wv * 32 + i * 8) * 64], 16, 0, 0);
        __syncthreads();

        short8_t a[2];
#pragma unroll
        for (int ks = 0; ks < 2; ks++) {
            int r = wv * 16 + fr;
            int u = (ks * 4 + fg) ^ (fr & 7);
            a[ks] = *(const short8_t*)&At[r * 64 + u * 8];
        }
#pragma unroll
        for (int nf = 0; nf < 8; nf++) {
#pragma unroll
            for (int ks = 0; ks < 2; ks++) {
                int r = nf * 16 + fr;
                int u = (ks * 4 + fg) ^ (fr & 7);
                short8_t b = *(const short8_t*)&Bt[r * 64 + u * 8];
                acc[nf] = MFMA(a[ks], b, acc[nf]);
            }
        }
        __syncthreads();
    }

#pragma unroll
    for (int nf = 0; nf < 8; nf++)
#pragma unroll
        for (int r = 0; r < 4; r++) {
            int dd = wv * 16 + fg * 4 + r;
            int pos = mloc + nf * 16 + fr;
            float v = acc[nf][r] + bias[o0 + dd];
            dstT[((size_t)bh * DK + dd) * SEQ + pos] = f2bf(v);
        }
}

// ---------------------------------------------------------------------------
// LSH flash attention, bucket-sorted, BUCKET-ALIGNED q-slots (balanced) +
// 2-phase double-buffered staging (STAGE(t+1) before compute(t), 1 barrier).
// Grid: 32 heads x 33 slots = 1056 flat, XCD-grouped (4 heads per XCD).
// ---------------------------------------------------------------------------
__global__ __launch_bounds__(256) void lsh_attn_kernel(
    const unsigned short* __restrict__ Qs,
    const unsigned short* __restrict__ Ks, const unsigned short* __restrict__ Vst,
    const int* __restrict__ qorder, const int* __restrict__ cnts,
    float* __restrict__ out)
{
    __shared__ unsigned short KtL[2][64 * 64];
    __shared__ unsigned short VtL[2][64 * 64];
    __shared__ unsigned short Pl[4][16][72];

    const int tid = threadIdx.x;
    const int lane = tid & 63;
    const int wv = tid >> 6;
    const int fr = lane & 15;
    const int fg = lane >> 4;

    // XCD-grouped mapping: 1056 = 8 XCD x (4 heads x 33 slots)
    const int flat = blockIdx.x;
    const int xcd = flat & 7;
    const int s2 = flat >> 3;                 // 0..131
    const int bh = (xcd << 2) + (s2 / 33);    // b*16 + h
    const int slot = s2 % 33;

    const int nq0 = cnts[bh];
    const int nk0 = cnts[32 + bh];
    const int c0 = (nq0 + 63) >> 6;           // q-tiles covering bucket 0

    int B, qlo, qhi;
    if (slot < c0) {
        B = 0; qlo = slot << 6; qhi = min(qlo + 64, nq0);
    } else {
        B = 1; qlo = nq0 + ((slot - c0) << 6);
        if (qlo >= SEQ) return;               // uniform: safe before barriers
        qhi = min(qlo + 64, SEQ);
    }
    const int klo = B ? (nk0 >> 6) : 0;
    const int khi = B ? (SEQ >> 6) : ((nk0 + 63) >> 6);
    const int nt = khi - klo;

    const size_t base = (size_t)bh * SEQ * DK;
    const unsigned short* Kb = Ks + base;                    // [pos][d]
    const unsigned short* Vb = Vst + (size_t)bh * DK * SEQ;  // [d][pos]

    const int srw = lane >> 3;
    const int su = lane & 7;

    // Q fragments (sorted rows qlo + wv*16 + fr; overshoot rows discarded at store)
    short8_t q_hi[2];
    {
        const size_t ro = base + (size_t)(qlo + wv * 16 + fr) * DK;
        q_hi[0] = *(const short8_t*)(Qs + ro + fg * 8);
        q_hi[1] = *(const short8_t*)(Qs + ro + 32 + fg * 8);
    }

    const int swz = fr & 7;
    const int u0 = ((fg ^ swz) << 3);
    const int u1 = (((4 + fg) ^ swz) << 3);

    const float C2 = 0.18033688011112042f;    // 0.125 * log2(e)
    const float B2 = -14.426950408889634f;    // -10 * log2(e)

    float psum[4] = {0.f, 0.f, 0.f, 0.f};
    f32x4 o_acc[4];
    const f32x4 fzero = {0.f, 0.f, 0.f, 0.f};
#pragma unroll
    for (int t = 0; t < 4; t++) o_acc[t] = fzero;

#define STAGE(T, BI)                                                          \
    {                                                                         \
        const int k0s = (T) << 6;                                             \
        _Pragma("unroll")                                                     \
        for (int i = 0; i < 2; i++) {                                         \
            const int r = wv * 16 + i * 8 + srw;                              \
            const int uo = ((su ^ (r & 7)) << 3);                             \
            __builtin_amdgcn_global_load_lds(                                 \
                (const void*)(Kb + (size_t)(k0s + r) * DK + uo),              \
                (void*)&KtL[BI][(wv * 16 + i * 8) * 64], 16, 0, 0);           \
            __builtin_amdgcn_global_load_lds(                                 \
                (const void*)(Vb + (size_t)r * SEQ + k0s + uo),               \
                (void*)&VtL[BI][(wv * 16 + i * 8) * 64], 16, 0, 0);           \
        }                                                                     \
    }

    STAGE(klo, 0);
    __syncthreads();
    int cur = 0;

    for (int i = 0; i < nt; i++) {
        if (i + 1 < nt) STAGE(klo + i + 1, cur ^ 1);   // prefetch next tile

        const int k0 = (klo + i) << 6;

        // ---- S = Q K^T (8 MFMA) ----
        f32x4 s[4];
#pragma unroll
        for (int kg = 0; kg < 4; kg++) {
            const int rr = (kg * 16 + fr) * 64;
            short8_t kc0 = *(const short8_t*)&KtL[cur][rr + u0];
            short8_t kc1 = *(const short8_t*)&KtL[cur][rr + u1];
            f32x4 a = fzero;
            a = MFMA(q_hi[0], kc0, a);
            a = MFMA(q_hi[1], kc1, a);
            s[kg] = a;
        }

        // ---- softmax: p = exp2(s*C2 + basev), basev per key column ----
        float basev[4];
#pragma unroll
        for (int kg = 0; kg < 4; kg++) {
            int cb = (k0 + kg * 16 + fr) >= nk0;
            basev[kg] = (cb == B) ? B2 : -1e9f;
        }
#pragma unroll
        for (int r = 0; r < 4; r++) {
#pragma unroll
            for (int kg = 0; kg < 4; kg++) {
                float p = exp2f(fmaf(s[kg][r], C2, basev[kg]));
                psum[r] += p;
                Pl[wv][fg * 4 + r][kg * 16 + fr] = f2bf(p);
            }
        }

        // ---- O += P V ----
        short8_t pa0 = *(const short8_t*)&Pl[wv][fr][fg * 8];
        short8_t pa1 = *(const short8_t*)&Pl[wv][fr][32 + fg * 8];
#pragma unroll
        for (int dt = 0; dt < 4; dt++) {
            const int rr = (dt * 16 + fr) * 64;
            short8_t v0 = *(const short8_t*)&VtL[cur][rr + u0];
            short8_t v1 = *(const short8_t*)&VtL[cur][rr + u1];
            o_acc[dt] = MFMA(pa0, v0, o_acc[dt]);
            o_acc[dt] = MFMA(pa1, v1, o_acc[dt]);
        }

        __syncthreads();   // drains prefetch + protects buffer reuse
        cur ^= 1;
    }
#undef STAGE

    // ---- final l-reduction over the 16 fr lanes ----
#pragma unroll
    for (int d = 1; d < 16; d <<= 1) {
#pragma unroll
        for (int r = 0; r < 4; r++) psum[r] += __shfl_xor(psum[r], d, 64);
    }

    // ---- epilogue: scatter rows back via qorder (rows < qhi only) ----
    const int b = bh >> 4, h = bh & 15;
#pragma unroll
    for (int r = 0; r < 4; r++) {
        const int qpos = qlo + wv * 16 + fg * 4 + r;
        if (qpos < qhi) {
            const int origq = qorder[(size_t)bh * SEQ + qpos];
            const float inv = 1.0f / psum[r];
#pragma unroll
            for (int dt = 0; dt < 4; dt++) {
                int dcol = dt * 16 + fr;
                out[((size_t)(b * SEQ + origq)) * DMODEL + h * DK + dcol] =
                    o_acc[dt][r] * inv;
            }
        }
    }
}

// ---------------------------------------------------------------------------

extern "C" void kernel_launch(void* const* d_in, const int* in_sizes, int n_in,
                              void* d_out, int out_size, void* d_ws, size_t ws_size,
                              hipStream_t stream)
{
    const float* query = (const float*)d_in[0];
    const float* key   = (const float*)d_in[1];
    const float* value = (const float*)d_in[2];
    const int* hash_q  = (const int*)d_in[3];
    const int* hash_k  = (const int*)d_in[4];
    const float* Wq    = (const float*)d_in[5];
    const float* bq    = (const float*)d_in[6];
    const float* Wk    = (const float*)d_in[7];
    const float* bk    = (const float*)d_in[8];
    const float* Wv    = (const float*)d_in[9];
    const float* bv    = (const float*)d_in[10];
    float* out = (float*)d_out;

    const size_t plane = (size_t)BATCH * NHEAD * SEQ * DK;   // 4,194,304 elems
    unsigned short* ws = (unsigned short*)d_ws;
    unsigned short* pQ    = ws;
    unsigned short* pK    = ws + plane;
    unsigned short* pVt   = ws + 2 * plane;
    unsigned short* Xslot = ws + 3 * plane;                   // 4M els
    unsigned short* Wslot = ws + 4 * plane;                   // 1M els
    int* ip = (int*)(ws + 4 * plane + (size_t)DMODEL * DMODEL);
    int* qorder = ip;                 // 32*2048
    int* korder = ip + 65536;         // 32*2048
    int* cnts   = ip + 131072;        // 64

    bucket_kernel<<<64, 256, 0, stream>>>(hash_q, hash_k, qorder, korder, cnts);

    dim3 gridN(NHEAD, (BATCH * SEQ) / 128);        // (16, 32)
    dim3 gridT((BATCH * SEQ) / 128, NHEAD);        // (32, 16)
    const int cvtBlocks = (int)((plane + (size_t)DMODEL * DMODEL) / 8 / 256);

    cvt_xw_kernel<<<cvtBlocks, 256, 0, stream>>>(query, Wq, Xslot, Wslot);
    proj_perm_nt<<<gridN, 256, 0, stream>>>(Xslot, Wslot, bq, qorder, pQ);

    cvt_xw_kernel<<<cvtBlocks, 256, 0, stream>>>(key, Wk, Xslot, Wslot);
    proj_perm_nt<<<gridN, 256, 0, stream>>>(Xslot, Wslot, bk, korder, pK);

    cvt_xw_kernel<<<cvtBlocks, 256, 0, stream>>>(value, Wv, Xslot, Wslot);
    proj_perm_tn<<<gridT, 256, 0, stream>>>(Xslot, Wslot, bv, korder, pVt);

    lsh_attn_kernel<<<dim3(1056), 256, 0, stream>>>(pQ, pK, pVt,
                                                    qorder, cnts, out);
}

// Round 8
// 132.337 us; speedup vs baseline: 1.1211x; 1.0138x over previous
//
#include <hip/hip_runtime.h>
#include <hip/hip_bf16.h>
#include <stdint.h>
#include <math.h>

#define NHEAD 16
#define DK 64
#define SEQ 2048
#define BATCH 2
#define DMODEL 1024

typedef __attribute__((ext_vector_type(8))) short short8_t;
typedef __attribute__((ext_vector_type(4))) short short4_t;
typedef __attribute__((ext_vector_type(4))) float f32x4;

#define MFMA(a, b, c) __builtin_amdgcn_mfma_f32_16x16x32_bf16(a, b, c, 0, 0, 0)
#define MFMA16(a, b, c) __builtin_amdgcn_mfma_f32_16x16x16bf16_1k(a, b, c, 0, 0, 0)

__device__ __forceinline__ unsigned short f2bf(float f) {
    union { __hip_bfloat16 b; unsigned short u; } c;
    c.b = __float2bfloat16(f);
    return c.u;
}

// ---------------------------------------------------------------------------
// bucket_kernel: per (bh, which) stable-partition indices by hash value.
// ---------------------------------------------------------------------------
__global__ __launch_bounds__(256) void bucket_kernel(
    const int* __restrict__ hq, const int* __restrict__ hk,
    int* __restrict__ qorder, int* __restrict__ korder, int* __restrict__ cnts)
{
    const int blk = blockIdx.x;          // 0..63
    const int bh = blk >> 1;
    const int which = blk & 1;
    const int* src = (which ? hk : hq) + (size_t)bh * SEQ;
    int* dst = (which ? korder : qorder) + (size_t)bh * SEQ;

    __shared__ int cnt[257];
    const int t = threadIdx.x;           // 0..255
    int h[8]; int c = 0;
#pragma unroll
    for (int j = 0; j < 8; j++) { h[j] = src[t * 8 + j]; c += (h[j] == 0); }
    cnt[t] = c;
    __syncthreads();
    if (t == 0) {
        int run = 0;
        for (int i = 0; i < 256; i++) { int v = cnt[i]; cnt[i] = run; run += v; }
        cnt[256] = run;
    }
    __syncthreads();
    const int nz = cnt[256];
    int zpos = cnt[t];
    int opos = nz + t * 8 - cnt[t];
#pragma unroll
    for (int j = 0; j < 8; j++) {
        int idx = t * 8 + j;
        if (h[j] == 0) dst[zpos++] = idx; else dst[opos++] = idx;
    }
    if (t == 0) cnts[which * 32 + bh] = nz;
}

// ---------------------------------------------------------------------------
// cvt_xw: X (4M f32) -> bf16, W (1M f32) -> bf16.
// ---------------------------------------------------------------------------
__global__ __launch_bounds__(256) void cvt_xw_kernel(
    const float* __restrict__ X, const float* __restrict__ W,
    unsigned short* __restrict__ Xb, unsigned short* __restrict__ Wb)
{
    const size_t t = (size_t)blockIdx.x * 256 + threadIdx.x;
    const float* src;
    unsigned short* dst;
    size_t i8;
    if (t < 524288) { src = X; dst = Xb; i8 = t * 8; }
    else            { src = W; dst = Wb; i8 = (t - 524288) * 8; }
    f32x4 v0 = *(const f32x4*)(src + i8);
    f32x4 v1 = *(const f32x4*)(src + i8 + 4);
    union { short8_t v; unsigned short u[8]; } o;
#pragma unroll
    for (int j = 0; j < 4; j++) {
        o.u[j]     = f2bf(v0[j]);
        o.u[4 + j] = f2bf(v1[j]);
    }
    *(short8_t*)(dst + i8) = o.v;
}

// ---------------------------------------------------------------------------
// proj_perm_nt: dst[b,h,pos,d] = (Xb[order] @ Wb^T + bias) in SORTED row order.
// ---------------------------------------------------------------------------
__global__ __launch_bounds__(256) void proj_perm_nt(
    const unsigned short* __restrict__ Xb,   // [4096][1024]
    const unsigned short* __restrict__ Wb,   // [1024][1024]
    const float* __restrict__ bias,
    const int* __restrict__ order,           // [32][2048]
    unsigned short* __restrict__ dst)        // [b,h,pos,d] bf16
{
    __shared__ unsigned short At[128 * 64];
    __shared__ unsigned short Bt[64 * 64];

    const int tid = threadIdx.x;
    const int lane = tid & 63;
    const int wv = tid >> 6;
    const int fr = lane & 15;
    const int fg = lane >> 4;
    const int m0 = blockIdx.y * 128;        // sorted-row tile (within one b)
    const int head = blockIdx.x;            // 0..15
    const int bb = m0 >> 11;
    const int bh = bb * NHEAD + head;
    const int n0 = head * 64;
    const int srw = lane >> 3;
    const int su = lane & 7;
    const int mloc = m0 & (SEQ - 1);
    const int* ordp = order + (size_t)bh * SEQ + mloc;

    const unsigned short* aSrc[4];
#pragma unroll
    for (int i = 0; i < 4; i++) {
        int r = wv * 32 + i * 8 + srw;
        int src_l = ordp[r];
        aSrc[i] = Xb + (size_t)(bb * SEQ + src_l) * DMODEL + ((su ^ (r & 7)) << 3);
    }
    const unsigned short* bSrc[2];
#pragma unroll
    for (int i = 0; i < 2; i++) {
        int r = wv * 16 + i * 8 + srw;
        bSrc[i] = Wb + (size_t)(n0 + r) * DMODEL + ((su ^ (r & 7)) << 3);
    }

    f32x4 acc[2][4];
    const f32x4 fzero = {0.f, 0.f, 0.f, 0.f};
#pragma unroll
    for (int mf = 0; mf < 2; mf++)
#pragma unroll
        for (int nf = 0; nf < 4; nf++) acc[mf][nf] = fzero;

    for (int k0 = 0; k0 < DMODEL; k0 += 64) {
#pragma unroll
        for (int i = 0; i < 4; i++)
            __builtin_amdgcn_global_load_lds(
                (const void*)(aSrc[i] + k0), (void*)&At[(wv * 32 + i * 8) * 64], 16, 0, 0);
#pragma unroll
        for (int i = 0; i < 2; i++)
            __builtin_amdgcn_global_load_lds(
                (const void*)(bSrc[i] + k0), (void*)&Bt[(wv * 16 + i * 8) * 64], 16, 0, 0);
        __syncthreads();

        short8_t a[2][2], b[4][2];
#pragma unroll
        for (int mf = 0; mf < 2; mf++)
#pragma unroll
            for (int ks = 0; ks < 2; ks++) {
                int r = wv * 32 + mf * 16 + fr;
                int u = (ks * 4 + fg) ^ (fr & 7);
                a[mf][ks] = *(const short8_t*)&At[r * 64 + u * 8];
            }
#pragma unroll
        for (int nf = 0; nf < 4; nf++)
#pragma unroll
            for (int ks = 0; ks < 2; ks++) {
                int r = nf * 16 + fr;
                int u = (ks * 4 + fg) ^ (fr & 7);
                b[nf][ks] = *(const short8_t*)&Bt[r * 64 + u * 8];
            }
#pragma unroll
        for (int ks = 0; ks < 2; ks++)
#pragma unroll
            for (int mf = 0; mf < 2; mf++)
#pragma unroll
                for (int nf = 0; nf < 4; nf++)
                    acc[mf][nf] = MFMA(a[mf][ks], b[nf][ks], acc[mf][nf]);
        __syncthreads();
    }

#pragma unroll
    for (int mf = 0; mf < 2; mf++)
#pragma unroll
        for (int nf = 0; nf < 4; nf++)
#pragma unroll
            for (int r = 0; r < 4; r++) {
                int pos = mloc + wv * 32 + mf * 16 + fg * 4 + r;
                int dd = nf * 16 + fr;
                float v = acc[mf][nf][r] + bias[n0 + dd];
                dst[((size_t)bh * SEQ + pos) * DK + dd] = f2bf(v);
            }
}

// ---------------------------------------------------------------------------
// proj_perm_tn: dstT[b,h,d,pos] = (Xb[korder] @ Wb^T + bias)^T, sorted cols.
// ---------------------------------------------------------------------------
__global__ __launch_bounds__(256) void proj_perm_tn(
    const unsigned short* __restrict__ Xb,   // [4096][1024]
    const unsigned short* __restrict__ Wb,   // [1024][1024]
    const float* __restrict__ bias,
    const int* __restrict__ order,           // [32][2048]
    unsigned short* __restrict__ dstT)       // [b,h,d,pos] bf16
{
    __shared__ unsigned short At[64 * 64];
    __shared__ unsigned short Bt[128 * 64];

    const int tid = threadIdx.x;
    const int lane = tid & 63;
    const int wv = tid >> 6;
    const int fr = lane & 15;
    const int fg = lane >> 4;
    const int m0 = blockIdx.x * 128;        // sorted key tile (within one b)
    const int head = blockIdx.y;
    const int bb = m0 >> 11;
    const int bh = bb * NHEAD + head;
    const int o0 = head * 64;
    const int srw = lane >> 3;
    const int su = lane & 7;
    const int mloc = m0 & (SEQ - 1);
    const int* ordp = order + (size_t)bh * SEQ + mloc;

    const unsigned short* aSrc[2];
#pragma unroll
    for (int i = 0; i < 2; i++) {
        int r = wv * 16 + i * 8 + srw;
        aSrc[i] = Wb + (size_t)(o0 + r) * DMODEL + ((su ^ (r & 7)) << 3);
    }
    const unsigned short* bSrc[4];
#pragma unroll
    for (int i = 0; i < 4; i++) {
        int r = wv * 32 + i * 8 + srw;
        int src_l = ordp[r];
        bSrc[i] = Xb + (size_t)(bb * SEQ + src_l) * DMODEL + ((su ^ (r & 7)) << 3);
    }

    f32x4 acc[8];
    const f32x4 fzero = {0.f, 0.f, 0.f, 0.f};
#pragma unroll
    for (int nf = 0; nf < 8; nf++) acc[nf] = fzero;

    for (int k0 = 0; k0 < DMODEL; k0 += 64) {
#pragma unroll
        for (int i = 0; i < 2; i++)
            __builtin_amdgcn_global_load_lds(
                (const void*)(aSrc[i] + k0), (void*)&At[(wv * 16 + i * 8) * 64], 16, 0, 0);
#pragma unroll
        for (int i = 0; i < 4; i++)
            __builtin_amdgcn_global_load_lds(
                (const void*)(bSrc[i] + k0), (void*)&Bt[(wv * 32 + i * 8) * 64], 16, 0, 0);
        __syncthreads();

        short8_t a[2];
#pragma unroll
        for (int ks = 0; ks < 2; ks++) {
            int r = wv * 16 + fr;
            int u = (ks * 4 + fg) ^ (fr & 7);
            a[ks] = *(const short8_t*)&At[r * 64 + u * 8];
        }
#pragma unroll
        for (int nf = 0; nf < 8; nf++) {
#pragma unroll
            for (int ks = 0; ks < 2; ks++) {
                int r = nf * 16 + fr;
                int u = (ks * 4 + fg) ^ (fr & 7);
                short8_t b = *(const short8_t*)&Bt[r * 64 + u * 8];
                acc[nf] = MFMA(a[ks], b, acc[nf]);
            }
        }
        __syncthreads();
    }

#pragma unroll
    for (int nf = 0; nf < 8; nf++)
#pragma unroll
        for (int r = 0; r < 4; r++) {
            int dd = wv * 16 + fg * 4 + r;
            int pos = mloc + nf * 16 + fr;
            float v = acc[nf][r] + bias[o0 + dd];
            dstT[((size_t)bh * DK + dd) * SEQ + pos] = f2bf(v);
        }
}

// ---------------------------------------------------------------------------
// LSH flash attention, bucket-sorted + bucket-aligned q-slots, swapped QK^T
// (S^T via mfma(K,Q)) and fully in-register PV via mfma_f32_16x16x16_bf16:
// lane holds S[q=fr][k=kg*16+fg*4+r] which IS the 16x16x16 B-fragment layout.
// No P LDS, no hash loads (mask = position compare, fast path off-boundary).
// LDS = exactly 32KB (K/V double buffer) -> 5 blocks/CU.
// ---------------------------------------------------------------------------
__global__ __launch_bounds__(256) void lsh_attn_kernel(
    const unsigned short* __restrict__ Qs,
    const unsigned short* __restrict__ Ks, const unsigned short* __restrict__ Vst,
    const int* __restrict__ qorder, const int* __restrict__ cnts,
    float* __restrict__ out)
{
    __shared__ unsigned short KtL[2][64 * 64];
    __shared__ unsigned short VtL[2][64 * 64];

    const int tid = threadIdx.x;
    const int lane = tid & 63;
    const int wv = tid >> 6;
    const int fr = lane & 15;
    const int fg = lane >> 4;

    // XCD-grouped mapping: 1056 = 8 XCD x (4 heads x 33 slots)
    const int flat = blockIdx.x;
    const int xcd = flat & 7;
    const int s2 = flat >> 3;                 // 0..131
    const int bh = (xcd << 2) + (s2 / 33);    // b*16 + h
    const int slot = s2 % 33;

    const int nq0 = cnts[bh];
    const int nk0 = cnts[32 + bh];
    const int c0 = (nq0 + 63) >> 6;           // q-tiles covering bucket 0

    int B, qlo, qhi;
    if (slot < c0) {
        B = 0; qlo = slot << 6; qhi = min(qlo + 64, nq0);
    } else {
        B = 1; qlo = nq0 + ((slot - c0) << 6);
        if (qlo >= SEQ) return;               // uniform: safe before barriers
        qhi = min(qlo + 64, SEQ);
    }
    const int klo = B ? (nk0 >> 6) : 0;
    const int khi = B ? (SEQ >> 6) : ((nk0 + 63) >> 6);
    const int nt = khi - klo;

    const size_t base = (size_t)bh * SEQ * DK;
    const unsigned short* Kb = Ks + base;                    // [pos][d]
    const unsigned short* Vb = Vst + (size_t)bh * DK * SEQ;  // [d][pos]

    const int srw = lane >> 3;
    const int su = lane & 7;

    // Q fragments (B-operand of swapped QK: lane fr = q-row qlo + wv*16 + fr)
    short8_t q_hi[2];
    {
        const size_t ro = base + (size_t)(qlo + wv * 16 + fr) * DK;
        q_hi[0] = *(const short8_t*)(Qs + ro + fg * 8);
        q_hi[1] = *(const short8_t*)(Qs + ro + 32 + fg * 8);
    }

    const int swz = fr & 7;
    const int u0 = ((fg ^ swz) << 3);
    const int u1 = (((4 + fg) ^ swz) << 3);
    // V^T b64-read offsets per kg (element offset within a row)
    int vuoff[4];
#pragma unroll
    for (int kg = 0; kg < 4; kg++)
        vuoff[kg] = (((kg * 2 + (fg >> 1)) ^ swz) << 3) + ((fg & 1) << 2);

    const float C2 = 0.18033688011112042f;    // 0.125 * log2(e)
    const float B2 = -14.426950408889634f;    // -10 * log2(e)

    float psum = 0.f;                         // per-lane (q = fr)
    f32x4 o_acc[4];
    const f32x4 fzero = {0.f, 0.f, 0.f, 0.f};
#pragma unroll
    for (int t = 0; t < 4; t++) o_acc[t] = fzero;

#define STAGE(T, BI)                                                          \
    {                                                                         \
        const int k0s = (T) << 6;                                             \
        _Pragma("unroll")                                                     \
        for (int i = 0; i < 2; i++) {                                         \
            const int r = wv * 16 + i * 8 + srw;                              \
            const int uo = ((su ^ (r & 7)) << 3);                             \
            __builtin_amdgcn_global_load_lds(                                 \
                (const void*)(Kb + (size_t)(k0s + r) * DK + uo),              \
                (void*)&KtL[BI][(wv * 16 + i * 8) * 64], 16, 0, 0);           \
            __builtin_amdgcn_global_load_lds(                                 \
                (const void*)(Vb + (size_t)r * SEQ + k0s + uo),               \
                (void*)&VtL[BI][(wv * 16 + i * 8) * 64], 16, 0, 0);           \
        }                                                                     \
    }

    STAGE(klo, 0);
    __syncthreads();
    int cur = 0;

    for (int i = 0; i < nt; i++) {
        if (i + 1 < nt) STAGE(klo + i + 1, cur ^ 1);   // prefetch next tile

        const int k0 = (klo + i) << 6;

        // ---- S^T = K Q^T (8 MFMA; A = K rows, B = Q) ----
        f32x4 s[4];
#pragma unroll
        for (int kg = 0; kg < 4; kg++) {
            const int rr = (kg * 16 + fr) * 64;
            short8_t kc0 = *(const short8_t*)&KtL[cur][rr + u0];
            short8_t kc1 = *(const short8_t*)&KtL[cur][rr + u1];
            f32x4 a = fzero;
            a = MFMA(kc0, q_hi[0], a);
            a = MFMA(kc1, q_hi[1], a);
            s[kg] = a;
        }

        // ---- softmax: p = exp2(s*C2 + B2); boundary tile masks by position ----
        short4_t pk[4];
        const bool mixed = B ? (k0 < nk0) : (k0 + 64 > nk0);
        if (!mixed) {
#pragma unroll
            for (int kg = 0; kg < 4; kg++) {
                union { short4_t v; unsigned short u[4]; } P;
#pragma unroll
                for (int r = 0; r < 4; r++) {
                    float p = exp2f(fmaf(s[kg][r], C2, B2));
                    psum += p;
                    P.u[r] = f2bf(p);
                }
                pk[kg] = P.v;
            }
        } else {
#pragma unroll
            for (int kg = 0; kg < 4; kg++) {
                union { short4_t v; unsigned short u[4]; } P;
#pragma unroll
                for (int r = 0; r < 4; r++) {
                    int cb = (k0 + kg * 16 + fg * 4 + r) >= nk0;
                    float basev = (cb == B) ? B2 : -1e9f;
                    float p = exp2f(fmaf(s[kg][r], C2, basev));
                    psum += p;
                    P.u[r] = f2bf(p);
                }
                pk[kg] = P.v;
            }
        }

        // ---- O^T += V^T P^T (16x16x16 MFMA; B-operand = pk, in-register) ----
#pragma unroll
        for (int dt = 0; dt < 4; dt++) {
            const int rb = (dt * 16 + fr) * 64;
            f32x4 acc = o_acc[dt];
#pragma unroll
            for (int kg = 0; kg < 4; kg++) {
                short4_t vf = *(const short4_t*)&VtL[cur][rb + vuoff[kg]];
                acc = MFMA16(vf, pk[kg], acc);
            }
            o_acc[dt] = acc;
        }

        __syncthreads();   // drains prefetch + protects buffer reuse
        cur ^= 1;
    }
#undef STAGE

    // ---- psum: reduce across the 4 fg groups (q = fr is lane-resident) ----
    psum += __shfl_xor(psum, 16, 64);
    psum += __shfl_xor(psum, 32, 64);

    // ---- epilogue: row q=fr scatter via qorder; cols contiguous -> float4 ----
    const int b = bh >> 4, h = bh & 15;
    const int qpos = qlo + wv * 16 + fr;
    if (qpos < qhi) {
        const int origq = qorder[(size_t)bh * SEQ + qpos];
        const float inv = 1.0f / psum;
        float* orow = out + ((size_t)(b * SEQ + origq)) * DMODEL + h * DK + fg * 4;
#pragma unroll
        for (int dt = 0; dt < 4; dt++) {
            f32x4 v = o_acc[dt];
            v *= inv;
            *(f32x4*)(orow + dt * 16) = v;
        }
    }
}

// ---------------------------------------------------------------------------

extern "C" void kernel_launch(void* const* d_in, const int* in_sizes, int n_in,
                              void* d_out, int out_size, void* d_ws, size_t ws_size,
                              hipStream_t stream)
{
    const float* query = (const float*)d_in[0];
    const float* key   = (const float*)d_in[1];
    const float* value = (const float*)d_in[2];
    const int* hash_q  = (const int*)d_in[3];
    const int* hash_k  = (const int*)d_in[4];
    const float* Wq    = (const float*)d_in[5];
    const float* bq    = (const float*)d_in[6];
    const float* Wk    = (const float*)d_in[7];
    const float* bk    = (const float*)d_in[8];
    const float* Wv    = (const float*)d_in[9];
    const float* bv    = (const float*)d_in[10];
    float* out = (float*)d_out;

    const size_t plane = (size_t)BATCH * NHEAD * SEQ * DK;   // 4,194,304 elems
    unsigned short* ws = (unsigned short*)d_ws;
    unsigned short* pQ    = ws;
    unsigned short* pK    = ws + plane;
    unsigned short* pVt   = ws + 2 * plane;
    unsigned short* Xslot = ws + 3 * plane;                   // 4M els
    unsigned short* Wslot = ws + 4 * plane;                   // 1M els
    int* ip = (int*)(ws + 4 * plane + (size_t)DMODEL * DMODEL);
    int* qorder = ip;                 // 32*2048
    int* korder = ip + 65536;         // 32*2048
    int* cnts   = ip + 131072;        // 64

    bucket_kernel<<<64, 256, 0, stream>>>(hash_q, hash_k, qorder, korder, cnts);

    dim3 gridN(NHEAD, (BATCH * SEQ) / 128);        // (16, 32)
    dim3 gridT((BATCH * SEQ) / 128, NHEAD);        // (32, 16)
    const int cvtBlocks = (int)((plane + (size_t)DMODEL * DMODEL) / 8 / 256);

    cvt_xw_kernel<<<cvtBlocks, 256, 0, stream>>>(query, Wq, Xslot, Wslot);
    proj_perm_nt<<<gridN, 256, 0, stream>>>(Xslot, Wslot, bq, qorder, pQ);

    cvt_xw_kernel<<<cvtBlocks, 256, 0, stream>>>(key, Wk, Xslot, Wslot);
    proj_perm_nt<<<gridN, 256, 0, stream>>>(Xslot, Wslot, bk, korder, pK);

    cvt_xw_kernel<<<cvtBlocks, 256, 0, stream>>>(value, Wv, Xslot, Wslot);
    proj_perm_tn<<<gridT, 256, 0, stream>>>(Xslot, Wslot, bv, korder, pVt);

    lsh_attn_kernel<<<dim3(1056), 256, 0, stream>>>(pQ, pK, pVt,
                                                    qorder, cnts, out);
}